// Round 3
// baseline (714.320 us; speedup 1.0000x reference)
//
#include <hip/hip_runtime.h>

constexpr int N_NODES = 50000;
constexpr int N_EDGES = 1600000;
constexpr int NREL    = 12;
constexpr int F_INPUT = 64;
constexpr int HID     = 128;
constexpr int NCLS    = 10;
constexpr int NGRAPH  = 256;
constexpr float BN_EPS = 1e-5f;

// counting-sort CSR parameters
constexpr int NB    = 391;                    // buckets of 128 nodes (dst >> 7)
constexpr int SEGB  = 128 * NREL;             // 1536 segments per bucket (rel-major)
constexpr int NOFF  = NB * SEGB;              // 600576 segment offsets (+1 sentinel)
constexpr int NBLK  = 392;                    // partition blocks
constexpr int PTPB  = 1024;
constexpr int EPB   = 4096;                   // edges per partition block (4/thread)

typedef float v4f __attribute__((ext_vector_type(4)));
typedef short s8b __attribute__((ext_vector_type(8)));

__device__ __forceinline__ unsigned f2bf(float f) {
    unsigned u = __float_as_uint(f);
    return (u + 0x7FFFu + ((u >> 16) & 1u)) >> 16;   // RNE fp32->bf16
}
__device__ __forceinline__ unsigned pack2(float a, float b) {
    return f2bf(a) | (f2bf(b) << 16);
}
__device__ __forceinline__ float bflo(unsigned u) { return __uint_as_float(u << 16); }
__device__ __forceinline__ float bfhi(unsigned u) { return __uint_as_float(u & 0xFFFF0000u); }

// ---------------- fused prep: zero scratch + pack weights + cast x + pcnt ----------------
constexpr int PQ0 = 64;                        // bn1: 256 floats (uint4)
constexpr int PQ1 = PQ0 + 64;                  // bn2
constexpr int PQ2 = PQ1 + 8192;                // psum: 32768 floats
constexpr int PQ3 = PQ2 + 13 * F_INPUT * HID;  // pack_w1
constexpr int PQ4 = PQ3 + 13 * HID * HID;      // pack_w2
constexpr int PQ5 = PQ4 + N_NODES * F_INPUT / 4; // cast x (float4)
constexpr int PQ6 = PQ5 + NGRAPH;              // pcnt binary search
constexpr int PREP_BLOCKS = (PQ6 + 255) / 256;

__global__ void prep(const float* __restrict__ Wrel1, const float* __restrict__ root1,
                     const float* __restrict__ Wrel2, const float* __restrict__ root2,
                     const float* __restrict__ x, const int* __restrict__ batch,
                     ushort* __restrict__ Wp1, ushort* __restrict__ Wp2,
                     ushort* __restrict__ xb,
                     float* __restrict__ bn1, float* __restrict__ bn2,
                     float* __restrict__ psum, float* __restrict__ pcnt) {
    int tid = blockIdx.x * 256 + threadIdx.x;
    const uint4 z = make_uint4(0, 0, 0, 0);
    if (tid < PQ0) { reinterpret_cast<uint4*>(bn1)[tid] = z; return; }
    if (tid < PQ1) { reinterpret_cast<uint4*>(bn2)[tid - PQ0] = z; return; }
    if (tid < PQ2) { reinterpret_cast<uint4*>(psum)[tid - PQ1] = z; return; }
    if (tid < PQ3) {
        int idx = tid - PQ2;                       // 13 * 8192
        int r = idx >> 13, rem = idx & 8191;
        int k = rem >> 7, n = rem & 127;
        const float* W = (r < NREL) ? (Wrel1 + (size_t)r * 8192) : root1;
        float v = W[k * HID + n];
        int b = k >> 5, kk = k & 31;
        int j = (n & 7) * 16 + (n >> 3);           // col-permuted fragment row
        Wp1[(((size_t)(r * 2 + b)) * HID + j) * 32 + kk] = (ushort)f2bf(v);
        return;
    }
    if (tid < PQ4) {
        int idx = tid - PQ3;                       // 13 * 16384
        int r = idx >> 14, rem = idx & 16383;
        int k = rem >> 7, n = rem & 127;
        const float* W = (r < NREL) ? (Wrel2 + (size_t)r * 16384) : root2;
        float v = W[k * HID + n];
        int b = k >> 5, kk = k & 31;
        int j = (n & 7) * 16 + (n >> 3);
        Wp2[(((size_t)(r * 4 + b)) * HID + j) * 32 + kk] = (ushort)f2bf(v);
        return;
    }
    if (tid < PQ5) {
        int i = tid - PQ4;
        float4 v = reinterpret_cast<const float4*>(x)[i];
        uint2 o;
        o.x = pack2(v.x, v.y);
        o.y = pack2(v.z, v.w);
        reinterpret_cast<uint2*>(xb)[i] = o;
        return;
    }
    if (tid < PQ6) {
        int g = tid - PQ5;
        int lo0 = 0, hi0 = N_NODES;
        while (lo0 < hi0) { int m = (lo0 + hi0) >> 1; if (batch[m] < g) lo0 = m + 1; else hi0 = m; }
        int lo1 = lo0, hi1 = N_NODES;
        while (lo1 < hi1) { int m = (lo1 + hi1) >> 1; if (batch[m] < g + 1) lo1 = m + 1; else hi1 = m; }
        pcnt[g] = (float)(lo1 - lo0);
    }
}

// ---------------- counting-sort CSR build (no far atomics) ----------------

__global__ __launch_bounds__(PTPB)
void part_hist(const int* __restrict__ dst, int* __restrict__ histG) {
    __shared__ int h[NB];
    int t = threadIdx.x, blk = blockIdx.x;
    if (t < NB) h[t] = 0;
    __syncthreads();
    int base = blk * EPB;
#pragma unroll
    for (int it = 0; it < EPB / PTPB; ++it) {
        int e = base + it * PTPB + t;
        if (e < N_EDGES) atomicAdd(&h[dst[e] >> 7], 1);
    }
    __syncthreads();
    if (t < NB) histG[blk * NB + t] = h[t];
}

__global__ __launch_bounds__(512)
void part_scanA(const int* __restrict__ histG, int* __restrict__ cursorG,
                int* __restrict__ bucketTot) {
    __shared__ int s[512];
    int t = threadIdx.x, b = blockIdx.x;
    int v = (t < NBLK) ? histG[t * NB + b] : 0;
    s[t] = v;
    __syncthreads();
    for (int d = 1; d < 512; d <<= 1) {
        int x = (t >= d) ? s[t - d] : 0;
        __syncthreads();
        s[t] += x;
        __syncthreads();
    }
    if (t < NBLK) cursorG[t * NB + b] = s[t] - v;   // exclusive prefix
    if (t == NBLK - 1) bucketTot[b] = s[t];
}

__global__ __launch_bounds__(512)
void part_scanB(const int* __restrict__ bucketTot, int* __restrict__ bucketBase) {
    __shared__ int s[512];
    int t = threadIdx.x;
    int v = (t < NB) ? bucketTot[t] : 0;
    s[t] = v;
    __syncthreads();
    for (int d = 1; d < 512; d <<= 1) {
        int x = (t >= d) ? s[t - d] : 0;
        __syncthreads();
        s[t] += x;
        __syncthreads();
    }
    if (t <= NB) bucketBase[t] = (t == 0) ? 0 : s[t - 1];
}

__global__ __launch_bounds__(PTPB)
void part_scatter(const int* __restrict__ src, const int* __restrict__ dst,
                  const int* __restrict__ et, const int* __restrict__ cursorG,
                  const int* __restrict__ bucketBase, uint* __restrict__ ebuck) {
    __shared__ int cur[NB];
    int t = threadIdx.x, blk = blockIdx.x;
    if (t < NB) cur[t] = cursorG[blk * NB + t] + bucketBase[t];
    __syncthreads();
    int base = blk * EPB;
#pragma unroll
    for (int it = 0; it < EPB / PTPB; ++it) {
        int e = base + it * PTPB + t;
        if (e < N_EDGES) {
            int d = dst[e];
            int b = d >> 7;
            int pos = atomicAdd(&cur[b], 1);
            ebuck[pos] = (uint)src[e] | ((uint)(d & 127) << 16) | ((uint)et[e] << 23);
        }
    }
}

// P4: per-bucket finalize, REL-MAJOR key: segments ordered (rel, localnode)
// so the fused GEMM's (bucket, rel, node-range) edge runs are contiguous.
__global__ __launch_bounds__(256)
void csr_finalize(const uint* __restrict__ ebuck, const int* __restrict__ bucketBase,
                  int* __restrict__ off, int* __restrict__ zrow) {
    __shared__ int cnt[SEGB];
    __shared__ int cur[SEGB];
    __shared__ int partial[256];
    int t = threadIdx.x, b = blockIdx.x;
    int eb0 = bucketBase[b], eb1 = bucketBase[b + 1];
#pragma unroll
    for (int i = 0; i < 6; ++i) cnt[t * 6 + i] = 0;
    __syncthreads();
    for (int e = eb0 + t; e < eb1; e += 256) {
        uint u = ebuck[e];
        int key = (int)(u >> 23) * 128 + (int)((u >> 16) & 127);   // rel-major
        atomicAdd(&cnt[key], 1);
    }
    __syncthreads();
    int loc[6];
    int sum = 0;
#pragma unroll
    for (int i = 0; i < 6; ++i) { loc[i] = sum; sum += cnt[t * 6 + i]; }
    partial[t] = sum;
    __syncthreads();
    for (int d = 1; d < 256; d <<= 1) {
        int v = (t >= d) ? partial[t - d] : 0;
        __syncthreads();
        partial[t] += v;
        __syncthreads();
    }
    int tbase = (t == 0) ? 0 : partial[t - 1];
#pragma unroll
    for (int i = 0; i < 6; ++i) {
        int s = t * 6 + i;
        int gpos = eb0 + tbase + loc[i];
        cur[s] = gpos;
        off[b * SEGB + s] = gpos;      // valid for all 1536 keys (empty -> zero-length)
    }
    __syncthreads();
    for (int e = eb0 + t; e < eb1; e += 256) {
        uint u = ebuck[e];
        int key = (int)(u >> 23) * 128 + (int)((u >> 16) & 127);
        int pos = atomicAdd(&cur[key], 1);
        zrow[pos] = (int)(u & 0xFFFFu);            // src node id
    }
    if (b == 0 && t == 0) off[NOFF] = N_EDGES;
}

// ---------------- FUSED mean-aggregate + concatenated-K GEMM ----------------
// One block per 128-node bucket. For each rel: build the mean A-tile in LDS
// (wave owns 32 rows; flat walk of its contiguous edge run, 8-deep prefetched
// gathers from LLC-resident X, register accumulator flushed at node
// boundaries - exclusive ownership, no atomics), then MFMA against Wp.
// Double-buffered A, one barrier per rel. M intermediate never exists.

template <int F>
__global__ __launch_bounds__(256)
void gemm_fused(const ushort* __restrict__ X, const int* __restrict__ offR,
                const int* __restrict__ zrow, const ushort* __restrict__ Wp,
                const float* __restrict__ bias, float* __restrict__ H,
                float* __restrict__ bn_sum, float* __restrict__ bn_sq) {
    constexpr int FP2 = F + 8;
    constexpr int KB  = F / 32;
    constexpr int CH  = 8;                 // edge chunk (loads in flight)
    __shared__ __align__(16) ushort A[2][128 * FP2];
    __shared__ float BNred[2][4][HID];
    const int t = threadIdx.x;
    const int b = blockIdx.x;
    const int n0 = b * 128;
    const int lane = t & 63, wave = t >> 6, q = lane >> 4, l16 = lane & 15;
    const int ln0 = wave * 32;             // wave owns tile rows [ln0, ln0+32)

    auto build = [&](int rel, ushort* Ab) {
        if (rel == NREL) {                  // root block: direct copy of X rows
#pragma unroll 4
            for (int i = 0; i < 32; ++i) {
                int n = n0 + ln0 + i;
                if constexpr (F == 64) {
                    ushort v = (n < N_NODES) ? X[(size_t)n * 64 + lane] : (ushort)0;
                    Ab[(ln0 + i) * FP2 + lane] = v;
                } else {
                    uint v = (n < N_NODES)
                        ? *reinterpret_cast<const uint*>(X + (size_t)n * 128 + lane * 2)
                        : 0u;
                    *reinterpret_cast<uint*>(Ab + (ln0 + i) * FP2 + lane * 2) = v;
                }
            }
            return;
        }
        const int base = b * SEGB + rel * 128 + ln0;
        const int e0 = offR[base];
        const int e1 = offR[base + 32];
        float a0 = 0.f, a1 = 0.f;
        int ln = 0;
        int eStart = e0;
        int eN = offR[base + 1];
        auto flush = [&](int cnt) {
            float winv = (cnt > 0) ? 1.f / (float)cnt : 0.f;
            if constexpr (F == 64)
                Ab[(ln0 + ln) * FP2 + lane] = (ushort)f2bf(a0 * winv);
            else
                *reinterpret_cast<uint*>(Ab + (ln0 + ln) * FP2 + lane * 2) =
                    pack2(a0 * winv, a1 * winv);
            a0 = 0.f; a1 = 0.f;
        };
        const int elast = e1 - 1;
        auto loadchunk = [&](int e, uint* uu) {
            int idx[CH];
#pragma unroll
            for (int j = 0; j < CH; ++j) idx[j] = zrow[min(e + j, elast)];
#pragma unroll
            for (int j = 0; j < CH; ++j) {
                if constexpr (F == 64)
                    uu[j] = X[(size_t)idx[j] * 64 + lane];
                else
                    uu[j] = *reinterpret_cast<const uint*>(X + (size_t)idx[j] * 128 + lane * 2);
            }
        };
        uint u[CH];
        if (e0 < e1) loadchunk(e0, u);
        for (int e = e0; e < e1; e += CH) {
            uint un[CH];
            if (e + CH < e1) loadchunk(e + CH, un);
#pragma unroll
            for (int j = 0; j < CH; ++j) {
                int ej = e + j;
                if (ej < e1) {
                    while (ej >= eN) {              // node boundary: flush + advance
                        flush(eN - eStart);
                        ++ln; eStart = eN; eN = offR[base + ln + 1];
                    }
                    a0 += bflo(u[j]);
                    if constexpr (F == 128) a1 += bfhi(u[j]);
                }
            }
#pragma unroll
            for (int j = 0; j < CH; ++j) u[j] = un[j];
        }
        while (ln < 32) {                           // trailing (incl. empty) nodes
            flush(eN - eStart);
            ++ln; eStart = eN;
            if (ln < 32) eN = offR[base + ln + 1];
        }
    };

    v4f acc[2][8];
#pragma unroll
    for (int st = 0; st < 2; ++st)
#pragma unroll
        for (int nt = 0; nt < 8; ++nt) acc[st][nt] = (v4f){0.f, 0.f, 0.f, 0.f};

    build(0, A[0]);
    for (int rel = 0; rel <= NREL; ++rel) {
        const int cur = rel & 1;
        __syncthreads();                    // A[cur] complete; A[cur^1] free
        if (rel < NREL) build(rel + 1, A[cur ^ 1]);
#pragma unroll
        for (int kb = 0; kb < KB; ++kb) {
            s8b bfr[8];
            const ushort* wb = Wp + ((size_t)(rel * KB + kb) * HID + l16) * 32 + q * 8;
#pragma unroll
            for (int nt = 0; nt < 8; ++nt)
                bfr[nt] = *reinterpret_cast<const s8b*>(wb + (size_t)nt * 16 * 32);
#pragma unroll
            for (int st = 0; st < 2; ++st) {
                s8b af = *reinterpret_cast<const s8b*>(
                    A[cur] + (ln0 + st * 16 + l16) * FP2 + kb * 32 + q * 8);
#pragma unroll
                for (int nt = 0; nt < 8; ++nt)
                    acc[st][nt] =
                        __builtin_amdgcn_mfma_f32_16x16x32_bf16(af, bfr[nt], acc[st][nt], 0, 0, 0);
            }
        }
    }

    // ---- epilogue: bias, fp32 H write, BN partial stats ----
    const int c0 = l16 * 8;    // lane l16 owns logical cols c0..c0+7 (Wp is col-permuted)
    float4 b4a = *reinterpret_cast<const float4*>(bias + c0);
    float4 b4b = *reinterpret_cast<const float4*>(bias + c0 + 4);
    float bv[8] = {b4a.x, b4a.y, b4a.z, b4a.w, b4b.x, b4b.y, b4b.z, b4b.w};
    float s[8], sq[8];
#pragma unroll
    for (int nt = 0; nt < 8; ++nt) { s[nt] = 0.f; sq[nt] = 0.f; }
#pragma unroll
    for (int st = 0; st < 2; ++st) {
#pragma unroll
        for (int rr = 0; rr < 4; ++rr) {
            int n = n0 + ln0 + st * 16 + q * 4 + rr;
            if (n < N_NODES) {
                float v[8];
#pragma unroll
                for (int nt = 0; nt < 8; ++nt) {
                    v[nt] = acc[st][nt][rr] + bv[nt];
                    s[nt] += v[nt];
                    sq[nt] += v[nt] * v[nt];
                }
                float* hr = H + (size_t)n * HID + c0;
                *reinterpret_cast<float4*>(hr)     = make_float4(v[0], v[1], v[2], v[3]);
                *reinterpret_cast<float4*>(hr + 4) = make_float4(v[4], v[5], v[6], v[7]);
            }
        }
    }
#pragma unroll
    for (int nt = 0; nt < 8; ++nt) {       // reduce across q (lanes l16, l16+16, +32, +48)
        s[nt]  += __shfl_xor(s[nt], 16);  s[nt]  += __shfl_xor(s[nt], 32);
        sq[nt] += __shfl_xor(sq[nt], 16); sq[nt] += __shfl_xor(sq[nt], 32);
    }
    if (q == 0) {
#pragma unroll
        for (int nt = 0; nt < 8; ++nt) {
            BNred[0][wave][c0 + nt] = s[nt];
            BNred[1][wave][c0 + nt] = sq[nt];
        }
    }
    __syncthreads();
    if (t < HID) {
        atomicAdd(&bn_sum[t], BNred[0][0][t] + BNred[0][1][t] + BNred[0][2][t] + BNred[0][3][t]);
    } else {
        int c = t - HID;
        atomicAdd(&bn_sq[c], BNred[1][0][c] + BNred[1][1][c] + BNred[1][2][c] + BNred[1][3][c]);
    }
}

// ---------------- BN(+finalize) + ReLU, emit bf16 ----------------

__global__ void bn_relu_bf16(const float* __restrict__ h, const float* __restrict__ bn_sum,
                             const float* __restrict__ bn_sq, const float* __restrict__ gamma,
                             const float* __restrict__ beta, ushort* __restrict__ outb) {
    __shared__ float CA[HID], CB[HID];
    int t = threadIdx.x;
    if (t < HID) {
        float mu = bn_sum[t] * (1.0f / N_NODES);
        float var = bn_sq[t] * (1.0f / N_NODES) - mu * mu;
        float a = gamma[t] / sqrtf(var + BN_EPS);
        CA[t] = a;
        CB[t] = beta[t] - a * mu;
    }
    __syncthreads();
    int i = blockIdx.x * 256 + t;  // float4 index
    constexpr int TOTAL = N_NODES * HID / 4;
    if (i < TOTAL) {
        int o4 = i & 31;
        float4 a = reinterpret_cast<const float4*>(CA)[o4];
        float4 b = reinterpret_cast<const float4*>(CB)[o4];
        float4 v = reinterpret_cast<const float4*>(h)[i];
        v.x = fmaxf(a.x * v.x + b.x, 0.f);
        v.y = fmaxf(a.y * v.y + b.y, 0.f);
        v.z = fmaxf(a.z * v.z + b.z, 0.f);
        v.w = fmaxf(a.w * v.w + b.w, 0.f);
        uint2 o;
        o.x = pack2(v.x, v.y);
        o.y = pack2(v.z, v.w);
        reinterpret_cast<uint2*>(outb)[i] = o;
    }
}

// ---------------- pooling (BN finalize + ReLU fused; batch sorted -> run-length) ----------------

__global__ void pool_bnrelu(const float* __restrict__ h, const float* __restrict__ bn_sum,
                            const float* __restrict__ bn_sq, const float* __restrict__ gamma,
                            const float* __restrict__ beta, const int* __restrict__ batch,
                            float* __restrict__ psum) {
    __shared__ float CA[HID], CB[HID];
    int t = threadIdx.x;
    if (t < HID) {
        float mu = bn_sum[t] * (1.0f / N_NODES);
        float var = bn_sq[t] * (1.0f / N_NODES) - mu * mu;
        float a = gamma[t] / sqrtf(var + BN_EPS);
        CA[t] = a;
        CB[t] = beta[t] - a * mu;
    }
    __syncthreads();
    int col = t & 127;
    int nb = blockIdx.x * 16 + (t >> 7) * 8;  // 8 consecutive nodes per thread
    float a = CA[col], b = CB[col];
    float run = 0.f;
    int curg = -1;
    for (int i = 0; i < 8; ++i) {
        int n = nb + i;
        if (n < N_NODES) {
            int g = batch[n];
            float v = fmaxf(a * h[(size_t)n * HID + col] + b, 0.f);
            if (g != curg) {
                if (curg >= 0) atomicAdd(&psum[curg * HID + col], run);
                run = 0.f;
                curg = g;
            }
            run += v;
        }
    }
    if (curg >= 0) atomicAdd(&psum[curg * HID + col], run);
}

__global__ void final_kernel(const float* __restrict__ psum, const float* __restrict__ pcnt,
                             const float* __restrict__ Wf, const float* __restrict__ bf,
                             float* __restrict__ out) {
    __shared__ float p[HID];
    int g = blockIdx.x, t = threadIdx.x;  // 64 threads
    float inv = 1.0f / fmaxf(pcnt[g], 1.0f);
    p[t] = psum[g * HID + t] * inv;
    p[t + 64] = psum[g * HID + t + 64] * inv;
    __syncthreads();
    if (t < NCLS) {
        float s = bf[t];
#pragma unroll 16
        for (int k = 0; k < HID; ++k) s += p[k] * Wf[k * NCLS + t];
        out[g * NCLS + t] = s;
    }
}

// ---------------- launch ----------------

extern "C" void kernel_launch(void* const* d_in, const int* in_sizes, int n_in,
                              void* d_out, int out_size, void* d_ws, size_t ws_size,
                              hipStream_t stream) {
    const float* x      = (const float*)d_in[0];
    const float* Wrel1  = (const float*)d_in[1];
    const float* root1  = (const float*)d_in[2];
    const float* bias1  = (const float*)d_in[3];
    const float* gamma1 = (const float*)d_in[4];
    const float* beta1  = (const float*)d_in[5];
    const float* Wrel2  = (const float*)d_in[6];
    const float* root2  = (const float*)d_in[7];
    const float* bias2  = (const float*)d_in[8];
    const float* gamma2 = (const float*)d_in[9];
    const float* beta2  = (const float*)d_in[10];
    const float* Wf     = (const float*)d_in[11];
    const float* bf     = (const float*)d_in[12];
    const int* ei       = (const int*)d_in[13];
    const int* et       = (const int*)d_in[14];
    const int* batch    = (const int*)d_in[15];
    const int* srcv = ei;
    const int* dstv = ei + N_EDGES;

    char* w = (char*)d_ws;
    auto alloc = [&](size_t bytes) -> char* {
        char* p = w;
        w += (bytes + 255) / 256 * 256;
        return p;
    };
    int* off     = (int*)alloc((size_t)(NOFF + 1) * 4);        // rel-major segment offsets
    int* zrow    = (int*)alloc((size_t)N_EDGES * 4);
    ushort* xb   = (ushort*)alloc((size_t)N_NODES * F_INPUT * 2);
    ushort* H1b  = (ushort*)alloc((size_t)N_NODES * HID * 2);
    ushort* Wp1  = (ushort*)alloc((size_t)13 * F_INPUT * HID * 2);
    ushort* Wp2  = (ushort*)alloc((size_t)13 * HID * HID * 2);
    float* bn1   = (float*)alloc(2 * HID * 4);  // sum | sq
    float* bn2   = (float*)alloc(2 * HID * 4);
    float* psum  = (float*)alloc((size_t)NGRAPH * HID * 4);
    float* pcnt  = (float*)alloc((size_t)NGRAPH * 4);
    float* Hbuf  = (float*)alloc((size_t)N_NODES * HID * 4);   // H1, later H2
    int* histG      = (int*)alloc((size_t)NBLK * NB * 4);
    int* cursorG    = (int*)alloc((size_t)NBLK * NB * 4);
    int* bucketTot  = (int*)alloc((size_t)NB * 4);
    int* bucketBase = (int*)alloc((size_t)(NB + 1) * 4);
    uint* ebuck     = (uint*)alloc((size_t)N_EDGES * 4);

    prep<<<PREP_BLOCKS, 256, 0, stream>>>(Wrel1, root1, Wrel2, root2, x, batch,
                                          Wp1, Wp2, xb, bn1, bn2, psum, pcnt);

    part_hist<<<NBLK, PTPB, 0, stream>>>(dstv, histG);
    part_scanA<<<NB, 512, 0, stream>>>(histG, cursorG, bucketTot);
    part_scanB<<<1, 512, 0, stream>>>(bucketTot, bucketBase);
    part_scatter<<<NBLK, PTPB, 0, stream>>>(srcv, dstv, et, cursorG, bucketBase, ebuck);
    csr_finalize<<<NB, 256, 0, stream>>>(ebuck, bucketBase, off, zrow);

    // ---- layer 1 (fused aggregate+GEMM, no M intermediate) ----
    gemm_fused<F_INPUT><<<NB, 256, 0, stream>>>(xb, off, zrow, Wp1, bias1,
                                                Hbuf, bn1, bn1 + HID);
    bn_relu_bf16<<<(N_NODES * HID / 4 + 255) / 256, 256, 0, stream>>>(Hbuf, bn1, bn1 + HID,
                                                                      gamma1, beta1, H1b);

    // ---- layer 2 ----
    gemm_fused<HID><<<NB, 256, 0, stream>>>(H1b, off, zrow, Wp2, bias2,
                                            Hbuf, bn2, bn2 + HID);

    pool_bnrelu<<<(N_NODES + 15) / 16, 256, 0, stream>>>(Hbuf, bn2, bn2 + HID, gamma2, beta2,
                                                         batch, psum);
    final_kernel<<<NGRAPH, 64, 0, stream>>>(psum, pcnt, Wf, bf, (float*)d_out);
}

// Round 4
// 485.858 us; speedup vs baseline: 1.4702x; 1.4702x over previous
//
#include <hip/hip_runtime.h>

constexpr int N_NODES = 50000;
constexpr int N_EDGES = 1600000;
constexpr int NREL    = 12;
constexpr int F_INPUT = 64;
constexpr int HID     = 128;
constexpr int NCLS    = 10;
constexpr int NGRAPH  = 256;
constexpr float BN_EPS = 1e-5f;

// counting-sort CSR parameters
constexpr int NB    = 391;                    // buckets of 128 nodes (dst >> 7)
constexpr int SEGB  = 128 * NREL;             // 1536 segments per bucket (rel-major)
constexpr int NOFF  = NB * SEGB;              // segment offsets (+1 sentinel)
constexpr int NBB   = NB * 2;                 // 782 half-bucket blocks for fused GEMM
constexpr int NBLK  = 392;                    // partition blocks
constexpr int PTPB  = 1024;
constexpr int EPB   = 4096;                   // edges per partition block (4/thread)

typedef float v4f __attribute__((ext_vector_type(4)));
typedef short s8b __attribute__((ext_vector_type(8)));

__device__ __forceinline__ unsigned f2bf(float f) {
    unsigned u = __float_as_uint(f);
    return (u + 0x7FFFu + ((u >> 16) & 1u)) >> 16;   // RNE fp32->bf16
}
__device__ __forceinline__ unsigned pack2(float a, float b) {
    return f2bf(a) | (f2bf(b) << 16);
}
__device__ __forceinline__ float bflo(unsigned u) { return __uint_as_float(u << 16); }
__device__ __forceinline__ float bfhi(unsigned u) { return __uint_as_float(u & 0xFFFF0000u); }

// ---------------- fused prep: zero scratch + pack weights + cast x + pcnt ----------------
constexpr int PQ0 = 64;                        // bn1: 256 floats (uint4)
constexpr int PQ1 = PQ0 + 64;                  // bn2
constexpr int PQ2 = PQ1 + 8192;                // psum: 32768 floats
constexpr int PQ3 = PQ2 + 13 * F_INPUT * HID;  // pack_w1
constexpr int PQ4 = PQ3 + 13 * HID * HID;      // pack_w2
constexpr int PQ5 = PQ4 + N_NODES * F_INPUT / 4; // cast x (float4)
constexpr int PQ6 = PQ5 + NGRAPH;              // pcnt binary search
constexpr int PREP_BLOCKS = (PQ6 + 255) / 256;

__global__ void prep(const float* __restrict__ Wrel1, const float* __restrict__ root1,
                     const float* __restrict__ Wrel2, const float* __restrict__ root2,
                     const float* __restrict__ x, const int* __restrict__ batch,
                     ushort* __restrict__ Wp1, ushort* __restrict__ Wp2,
                     ushort* __restrict__ xb,
                     float* __restrict__ bn1, float* __restrict__ bn2,
                     float* __restrict__ psum, float* __restrict__ pcnt) {
    int tid = blockIdx.x * 256 + threadIdx.x;
    const uint4 z = make_uint4(0, 0, 0, 0);
    if (tid < PQ0) { reinterpret_cast<uint4*>(bn1)[tid] = z; return; }
    if (tid < PQ1) { reinterpret_cast<uint4*>(bn2)[tid - PQ0] = z; return; }
    if (tid < PQ2) { reinterpret_cast<uint4*>(psum)[tid - PQ1] = z; return; }
    if (tid < PQ3) {
        int idx = tid - PQ2;                       // 13 * 8192
        int r = idx >> 13, rem = idx & 8191;
        int k = rem >> 7, n = rem & 127;
        const float* W = (r < NREL) ? (Wrel1 + (size_t)r * 8192) : root1;
        float v = W[k * HID + n];
        int b = k >> 5, kk = k & 31;
        int j = (n & 7) * 16 + (n >> 3);           // col-permuted fragment row
        Wp1[(((size_t)(r * 2 + b)) * HID + j) * 32 + kk] = (ushort)f2bf(v);
        return;
    }
    if (tid < PQ4) {
        int idx = tid - PQ3;                       // 13 * 16384
        int r = idx >> 14, rem = idx & 16383;
        int k = rem >> 7, n = rem & 127;
        const float* W = (r < NREL) ? (Wrel2 + (size_t)r * 16384) : root2;
        float v = W[k * HID + n];
        int b = k >> 5, kk = k & 31;
        int j = (n & 7) * 16 + (n >> 3);
        Wp2[(((size_t)(r * 4 + b)) * HID + j) * 32 + kk] = (ushort)f2bf(v);
        return;
    }
    if (tid < PQ5) {
        int i = tid - PQ4;
        float4 v = reinterpret_cast<const float4*>(x)[i];
        uint2 o;
        o.x = pack2(v.x, v.y);
        o.y = pack2(v.z, v.w);
        reinterpret_cast<uint2*>(xb)[i] = o;
        return;
    }
    if (tid < PQ6) {
        int g = tid - PQ5;
        int lo0 = 0, hi0 = N_NODES;
        while (lo0 < hi0) { int m = (lo0 + hi0) >> 1; if (batch[m] < g) lo0 = m + 1; else hi0 = m; }
        int lo1 = lo0, hi1 = N_NODES;
        while (lo1 < hi1) { int m = (lo1 + hi1) >> 1; if (batch[m] < g + 1) lo1 = m + 1; else hi1 = m; }
        pcnt[g] = (float)(lo1 - lo0);
    }
}

// ---------------- counting-sort CSR build (no far atomics) ----------------

__global__ __launch_bounds__(PTPB)
void part_hist(const int* __restrict__ dst, int* __restrict__ histG) {
    __shared__ int h[NB];
    int t = threadIdx.x, blk = blockIdx.x;
    if (t < NB) h[t] = 0;
    __syncthreads();
    int base = blk * EPB;
#pragma unroll
    for (int it = 0; it < EPB / PTPB; ++it) {
        int e = base + it * PTPB + t;
        if (e < N_EDGES) atomicAdd(&h[dst[e] >> 7], 1);
    }
    __syncthreads();
    if (t < NB) histG[blk * NB + t] = h[t];
}

__global__ __launch_bounds__(512)
void part_scanA(const int* __restrict__ histG, int* __restrict__ cursorG,
                int* __restrict__ bucketTot) {
    __shared__ int s[512];
    int t = threadIdx.x, b = blockIdx.x;
    int v = (t < NBLK) ? histG[t * NB + b] : 0;
    s[t] = v;
    __syncthreads();
    for (int d = 1; d < 512; d <<= 1) {
        int x = (t >= d) ? s[t - d] : 0;
        __syncthreads();
        s[t] += x;
        __syncthreads();
    }
    if (t < NBLK) cursorG[t * NB + b] = s[t] - v;   // exclusive prefix
    if (t == NBLK - 1) bucketTot[b] = s[t];
}

__global__ __launch_bounds__(512)
void part_scanB(const int* __restrict__ bucketTot, int* __restrict__ bucketBase) {
    __shared__ int s[512];
    int t = threadIdx.x;
    int v = (t < NB) ? bucketTot[t] : 0;
    s[t] = v;
    __syncthreads();
    for (int d = 1; d < 512; d <<= 1) {
        int x = (t >= d) ? s[t - d] : 0;
        __syncthreads();
        s[t] += x;
        __syncthreads();
    }
    if (t <= NB) bucketBase[t] = (t == 0) ? 0 : s[t - 1];
}

__global__ __launch_bounds__(PTPB)
void part_scatter(const int* __restrict__ src, const int* __restrict__ dst,
                  const int* __restrict__ et, const int* __restrict__ cursorG,
                  const int* __restrict__ bucketBase, uint* __restrict__ ebuck) {
    __shared__ int cur[NB];
    int t = threadIdx.x, blk = blockIdx.x;
    if (t < NB) cur[t] = cursorG[blk * NB + t] + bucketBase[t];
    __syncthreads();
    int base = blk * EPB;
#pragma unroll
    for (int it = 0; it < EPB / PTPB; ++it) {
        int e = base + it * PTPB + t;
        if (e < N_EDGES) {
            int d = dst[e];
            int b = d >> 7;
            int pos = atomicAdd(&cur[b], 1);
            ebuck[pos] = (uint)src[e] | ((uint)(d & 127) << 16) | ((uint)et[e] << 23);
        }
    }
}

// P4: per-bucket finalize, REL-MAJOR key: edge list sorted by (bucket, rel, localnode).
// zpack[e] = src | (localnode << 16) -> the fused build detects node boundaries
// from the stream itself (no offset pointer-chase in the inner loop).
__global__ __launch_bounds__(256)
void csr_finalize(const uint* __restrict__ ebuck, const int* __restrict__ bucketBase,
                  int* __restrict__ off, uint* __restrict__ zpack) {
    __shared__ int cnt[SEGB];
    __shared__ int cur[SEGB];
    __shared__ int partial[256];
    int t = threadIdx.x, b = blockIdx.x;
    int eb0 = bucketBase[b], eb1 = bucketBase[b + 1];
#pragma unroll
    for (int i = 0; i < 6; ++i) cnt[t * 6 + i] = 0;
    __syncthreads();
    for (int e = eb0 + t; e < eb1; e += 256) {
        uint u = ebuck[e];
        int key = (int)(u >> 23) * 128 + (int)((u >> 16) & 127);   // rel-major
        atomicAdd(&cnt[key], 1);
    }
    __syncthreads();
    int loc[6];
    int sum = 0;
#pragma unroll
    for (int i = 0; i < 6; ++i) { loc[i] = sum; sum += cnt[t * 6 + i]; }
    partial[t] = sum;
    __syncthreads();
    for (int d = 1; d < 256; d <<= 1) {
        int v = (t >= d) ? partial[t - d] : 0;
        __syncthreads();
        partial[t] += v;
        __syncthreads();
    }
    int tbase = (t == 0) ? 0 : partial[t - 1];
#pragma unroll
    for (int i = 0; i < 6; ++i) {
        int s = t * 6 + i;
        int gpos = eb0 + tbase + loc[i];
        cur[s] = gpos;
        off[b * SEGB + s] = gpos;      // all 1536 keys (empty -> zero-length)
    }
    __syncthreads();
    for (int e = eb0 + t; e < eb1; e += 256) {
        uint u = ebuck[e];
        int key = (int)(u >> 23) * 128 + (int)((u >> 16) & 127);
        int pos = atomicAdd(&cur[key], 1);
        zpack[pos] = u & 0x7FFFFFu;                // src(16) | localnode(7)
    }
    if (b == 0 && t == 0) off[NOFF] = N_EDGES;
}

// ---------------- FUSED mean-aggregate + concatenated-K GEMM (wave-decoupled) ------------
// Block = 64 nodes (half bucket), 4 INDEPENDENT waves; wave owns 16 rows.
// Per rel: wave builds its private 16-row mean A-strip in LDS (flat walk of its
// contiguous edge run; node boundaries detected from zpack's localnode field ->
// no dependent offset loads; 8-edge prefetched gathers from L2/LLC-resident X),
// then MFMAs the strip against Wp. Per-wave double buffer, NO main-loop barriers.

template <int F>
__global__ __launch_bounds__(256)
void gemm_fused(const ushort* __restrict__ X, const int* __restrict__ offR,
                const uint* __restrict__ zpack, const ushort* __restrict__ Wp,
                const float* __restrict__ bias, float* __restrict__ H,
                float* __restrict__ bn_sum, float* __restrict__ bn_sq) {
    constexpr int FP2 = F + 8;
    constexpr int KB  = F / 32;
    constexpr int CH  = 8;                 // edges in flight
    __shared__ __align__(16) ushort A[4][2][16 * FP2];
    __shared__ float BNred[2][4][HID];
    const int t = threadIdx.x;
    const int lane = t & 63, wave = t >> 6, q = lane >> 4, l16 = lane & 15;
    const int bid = blockIdx.x;
    const int bucket = bid >> 1, h = bid & 1;
    const int rowbase = h * 64 + wave * 16;            // first local row of this wave
    const int n0 = bucket * 128 + rowbase;             // first global node of this wave
    const int obase = bucket * SEGB + rowbase;         // + rel*128 -> run start index

    ushort* Aw0 = A[wave][0];
    ushort* Aw1 = A[wave][1];

    auto zerorow = [&](ushort* Ab, int r) {
        if constexpr (F == 64) Ab[r * FP2 + lane] = 0;
        else *reinterpret_cast<uint*>(Ab + r * FP2 + lane * 2) = 0u;
    };

    float a0, a1;
    auto build = [&](int rel, ushort* Ab) {
        if (rel == NREL) {                  // root block: direct copy of X rows
#pragma unroll 4
            for (int i = 0; i < 16; ++i) {
                int n = n0 + i;
                if constexpr (F == 64) {
                    Ab[i * FP2 + lane] = (n < N_NODES) ? X[(size_t)n * 64 + lane] : (ushort)0;
                } else {
                    uint v = (n < N_NODES)
                        ? *reinterpret_cast<const uint*>(X + (size_t)n * 128 + lane * 2) : 0u;
                    *reinterpret_cast<uint*>(Ab + i * FP2 + lane * 2) = v;
                }
            }
            return;
        }
        const int i0 = obase + rel * 128;
        const int e0 = offR[i0];            // wave-uniform broadcast loads
        const int e1 = offR[i0 + 16];
        if (e0 >= e1) {
            for (int r = 0; r < 16; ++r) zerorow(Ab, r);
            return;
        }
        a0 = 0.f; a1 = 0.f;
        int ln = 0, eStart = e0;
        auto flush = [&](int r, int cntE) {
            float winv = (cntE > 0) ? 1.f / (float)cntE : 0.f;
            if constexpr (F == 64)
                Ab[r * FP2 + lane] = (ushort)f2bf(a0 * winv);
            else
                *reinterpret_cast<uint*>(Ab + r * FP2 + lane * 2) = pack2(a0 * winv, a1 * winv);
            a0 = 0.f; a1 = 0.f;
        };
        const int elast = e1 - 1;
        auto ldpk = [&](int e, uint* p) {
#pragma unroll
            for (int j = 0; j < CH; ++j) p[j] = zpack[min(e + j, elast)];
        };
        auto ldux = [&](const uint* p, uint* u) {
#pragma unroll
            for (int j = 0; j < CH; ++j) {
                int s = (int)(p[j] & 0xFFFFu);
                if constexpr (F == 64)
                    u[j] = X[(size_t)s * 64 + lane];
                else
                    u[j] = *reinterpret_cast<const uint*>(X + (size_t)s * 128 + lane * 2);
            }
        };
        uint pk[CH], ux[CH];
        ldpk(e0, pk);
        ldux(pk, ux);
        for (int e = e0; e < e1; e += CH) {
            uint pn[CH], un[CH];
            if (e + CH < e1) { ldpk(e + CH, pn); ldux(pn, un); }
#pragma unroll
            for (int j = 0; j < CH; ++j) {
                int ej = e + j;
                if (ej < e1) {                         // wave-uniform
                    int ld = (int)(pk[j] >> 16) - rowbase;
                    if (ld != ln) {                    // node boundary from stream
                        flush(ln, ej - eStart);
                        for (int z = ln + 1; z < ld; ++z) zerorow(Ab, z);
                        ln = ld; eStart = ej;
                    }
                    a0 += bflo(ux[j]);
                    if constexpr (F == 128) a1 += bfhi(ux[j]);
                }
            }
#pragma unroll
            for (int j = 0; j < CH; ++j) { pk[j] = pn[j]; ux[j] = un[j]; }
        }
        flush(ln, e1 - eStart);
        for (int z = ln + 1; z < 16; ++z) zerorow(Ab, z);
    };

    v4f acc[8];
#pragma unroll
    for (int nt = 0; nt < 8; ++nt) acc[nt] = (v4f){0.f, 0.f, 0.f, 0.f};

    build(0, Aw0);
    for (int rel = 0; rel <= NREL; ++rel) {
        ushort* Acur = (rel & 1) ? Aw1 : Aw0;
        ushort* Anxt = (rel & 1) ? Aw0 : Aw1;
        if (rel < NREL) build(rel + 1, Anxt);   // overlaps with MFMA below (per-wave dbuf)
#pragma unroll
        for (int kb = 0; kb < KB; ++kb) {
            s8b bfr[8];
            const ushort* wb = Wp + ((size_t)(rel * KB + kb) * HID + l16) * 32 + q * 8;
#pragma unroll
            for (int nt = 0; nt < 8; ++nt)
                bfr[nt] = *reinterpret_cast<const s8b*>(wb + (size_t)nt * 16 * 32);
            s8b af = *reinterpret_cast<const s8b*>(Acur + l16 * FP2 + kb * 32 + q * 8);
#pragma unroll
            for (int nt = 0; nt < 8; ++nt)
                acc[nt] = __builtin_amdgcn_mfma_f32_16x16x32_bf16(af, bfr[nt], acc[nt], 0, 0, 0);
        }
    }

    // ---- epilogue: bias, fp32 H write, BN partial stats ----
    const int c0 = l16 * 8;    // lane l16 owns logical cols c0..c0+7 (Wp is col-permuted)
    float4 b4a = *reinterpret_cast<const float4*>(bias + c0);
    float4 b4b = *reinterpret_cast<const float4*>(bias + c0 + 4);
    float bv[8] = {b4a.x, b4a.y, b4a.z, b4a.w, b4b.x, b4b.y, b4b.z, b4b.w};
    float s[8], sq[8];
#pragma unroll
    for (int nt = 0; nt < 8; ++nt) { s[nt] = 0.f; sq[nt] = 0.f; }
#pragma unroll
    for (int rr = 0; rr < 4; ++rr) {
        int n = n0 + q * 4 + rr;
        if (n < N_NODES) {
            float v[8];
#pragma unroll
            for (int nt = 0; nt < 8; ++nt) {
                v[nt] = acc[nt][rr] + bv[nt];
                s[nt] += v[nt];
                sq[nt] += v[nt] * v[nt];
            }
            float* hr = H + (size_t)n * HID + c0;
            *reinterpret_cast<float4*>(hr)     = make_float4(v[0], v[1], v[2], v[3]);
            *reinterpret_cast<float4*>(hr + 4) = make_float4(v[4], v[5], v[6], v[7]);
        }
    }
#pragma unroll
    for (int nt = 0; nt < 8; ++nt) {       // reduce across q (lanes l16, l16+16, +32, +48)
        s[nt]  += __shfl_xor(s[nt], 16);  s[nt]  += __shfl_xor(s[nt], 32);
        sq[nt] += __shfl_xor(sq[nt], 16); sq[nt] += __shfl_xor(sq[nt], 32);
    }
    if (q == 0) {
#pragma unroll
        for (int nt = 0; nt < 8; ++nt) {
            BNred[0][wave][c0 + nt] = s[nt];
            BNred[1][wave][c0 + nt] = sq[nt];
        }
    }
    __syncthreads();                        // the only block-wide barrier
    if (t < HID) {
        atomicAdd(&bn_sum[t], BNred[0][0][t] + BNred[0][1][t] + BNred[0][2][t] + BNred[0][3][t]);
    } else {
        int c = t - HID;
        atomicAdd(&bn_sq[c], BNred[1][0][c] + BNred[1][1][c] + BNred[1][2][c] + BNred[1][3][c]);
    }
}

// ---------------- BN(+finalize) + ReLU, emit bf16 ----------------

__global__ void bn_relu_bf16(const float* __restrict__ h, const float* __restrict__ bn_sum,
                             const float* __restrict__ bn_sq, const float* __restrict__ gamma,
                             const float* __restrict__ beta, ushort* __restrict__ outb) {
    __shared__ float CA[HID], CB[HID];
    int t = threadIdx.x;
    if (t < HID) {
        float mu = bn_sum[t] * (1.0f / N_NODES);
        float var = bn_sq[t] * (1.0f / N_NODES) - mu * mu;
        float a = gamma[t] / sqrtf(var + BN_EPS);
        CA[t] = a;
        CB[t] = beta[t] - a * mu;
    }
    __syncthreads();
    int i = blockIdx.x * 256 + t;  // float4 index
    constexpr int TOTAL = N_NODES * HID / 4;
    if (i < TOTAL) {
        int o4 = i & 31;
        float4 a = reinterpret_cast<const float4*>(CA)[o4];
        float4 b = reinterpret_cast<const float4*>(CB)[o4];
        float4 v = reinterpret_cast<const float4*>(h)[i];
        v.x = fmaxf(a.x * v.x + b.x, 0.f);
        v.y = fmaxf(a.y * v.y + b.y, 0.f);
        v.z = fmaxf(a.z * v.z + b.z, 0.f);
        v.w = fmaxf(a.w * v.w + b.w, 0.f);
        uint2 o;
        o.x = pack2(v.x, v.y);
        o.y = pack2(v.z, v.w);
        reinterpret_cast<uint2*>(outb)[i] = o;
    }
}

// ---------------- pooling (BN finalize + ReLU fused; batch sorted -> run-length) ----------------

__global__ void pool_bnrelu(const float* __restrict__ h, const float* __restrict__ bn_sum,
                            const float* __restrict__ bn_sq, const float* __restrict__ gamma,
                            const float* __restrict__ beta, const int* __restrict__ batch,
                            float* __restrict__ psum) {
    __shared__ float CA[HID], CB[HID];
    int t = threadIdx.x;
    if (t < HID) {
        float mu = bn_sum[t] * (1.0f / N_NODES);
        float var = bn_sq[t] * (1.0f / N_NODES) - mu * mu;
        float a = gamma[t] / sqrtf(var + BN_EPS);
        CA[t] = a;
        CB[t] = beta[t] - a * mu;
    }
    __syncthreads();
    int col = t & 127;
    int nb = blockIdx.x * 16 + (t >> 7) * 8;  // 8 consecutive nodes per thread
    float a = CA[col], b = CB[col];
    float run = 0.f;
    int curg = -1;
    for (int i = 0; i < 8; ++i) {
        int n = nb + i;
        if (n < N_NODES) {
            int g = batch[n];
            float v = fmaxf(a * h[(size_t)n * HID + col] + b, 0.f);
            if (g != curg) {
                if (curg >= 0) atomicAdd(&psum[curg * HID + col], run);
                run = 0.f;
                curg = g;
            }
            run += v;
        }
    }
    if (curg >= 0) atomicAdd(&psum[curg * HID + col], run);
}

__global__ void final_kernel(const float* __restrict__ psum, const float* __restrict__ pcnt,
                             const float* __restrict__ Wf, const float* __restrict__ bf,
                             float* __restrict__ out) {
    __shared__ float p[HID];
    int g = blockIdx.x, t = threadIdx.x;  // 64 threads
    float inv = 1.0f / fmaxf(pcnt[g], 1.0f);
    p[t] = psum[g * HID + t] * inv;
    p[t + 64] = psum[g * HID + t + 64] * inv;
    __syncthreads();
    if (t < NCLS) {
        float s = bf[t];
#pragma unroll 16
        for (int k = 0; k < HID; ++k) s += p[k] * Wf[k * NCLS + t];
        out[g * NCLS + t] = s;
    }
}

// ---------------- launch ----------------

extern "C" void kernel_launch(void* const* d_in, const int* in_sizes, int n_in,
                              void* d_out, int out_size, void* d_ws, size_t ws_size,
                              hipStream_t stream) {
    const float* x      = (const float*)d_in[0];
    const float* Wrel1  = (const float*)d_in[1];
    const float* root1  = (const float*)d_in[2];
    const float* bias1  = (const float*)d_in[3];
    const float* gamma1 = (const float*)d_in[4];
    const float* beta1  = (const float*)d_in[5];
    const float* Wrel2  = (const float*)d_in[6];
    const float* root2  = (const float*)d_in[7];
    const float* bias2  = (const float*)d_in[8];
    const float* gamma2 = (const float*)d_in[9];
    const float* beta2  = (const float*)d_in[10];
    const float* Wf     = (const float*)d_in[11];
    const float* bf     = (const float*)d_in[12];
    const int* ei       = (const int*)d_in[13];
    const int* et       = (const int*)d_in[14];
    const int* batch    = (const int*)d_in[15];
    const int* srcv = ei;
    const int* dstv = ei + N_EDGES;

    char* w = (char*)d_ws;
    auto alloc = [&](size_t bytes) -> char* {
        char* p = w;
        w += (bytes + 255) / 256 * 256;
        return p;
    };
    int* off     = (int*)alloc((size_t)(NOFF + 1) * 4);        // rel-major segment offsets
    uint* zpack  = (uint*)alloc((size_t)N_EDGES * 4);          // src | localnode<<16
    ushort* xb   = (ushort*)alloc((size_t)N_NODES * F_INPUT * 2);
    ushort* H1b  = (ushort*)alloc((size_t)N_NODES * HID * 2);
    ushort* Wp1  = (ushort*)alloc((size_t)13 * F_INPUT * HID * 2);
    ushort* Wp2  = (ushort*)alloc((size_t)13 * HID * HID * 2);
    float* bn1   = (float*)alloc(2 * HID * 4);  // sum | sq
    float* bn2   = (float*)alloc(2 * HID * 4);
    float* psum  = (float*)alloc((size_t)NGRAPH * HID * 4);
    float* pcnt  = (float*)alloc((size_t)NGRAPH * 4);
    float* Hbuf  = (float*)alloc((size_t)N_NODES * HID * 4);   // H1, later H2
    int* histG      = (int*)alloc((size_t)NBLK * NB * 4);
    int* cursorG    = (int*)alloc((size_t)NBLK * NB * 4);
    int* bucketTot  = (int*)alloc((size_t)NB * 4);
    int* bucketBase = (int*)alloc((size_t)(NB + 1) * 4);
    uint* ebuck     = (uint*)alloc((size_t)N_EDGES * 4);

    prep<<<PREP_BLOCKS, 256, 0, stream>>>(Wrel1, root1, Wrel2, root2, x, batch,
                                          Wp1, Wp2, xb, bn1, bn2, psum, pcnt);

    part_hist<<<NBLK, PTPB, 0, stream>>>(dstv, histG);
    part_scanA<<<NB, 512, 0, stream>>>(histG, cursorG, bucketTot);
    part_scanB<<<1, 512, 0, stream>>>(bucketTot, bucketBase);
    part_scatter<<<NBLK, PTPB, 0, stream>>>(srcv, dstv, et, cursorG, bucketBase, ebuck);
    csr_finalize<<<NB, 256, 0, stream>>>(ebuck, bucketBase, off, zpack);

    // ---- layer 1 (fused aggregate+GEMM, no M intermediate) ----
    gemm_fused<F_INPUT><<<NBB, 256, 0, stream>>>(xb, off, zpack, Wp1, bias1,
                                                 Hbuf, bn1, bn1 + HID);
    bn_relu_bf16<<<(N_NODES * HID / 4 + 255) / 256, 256, 0, stream>>>(Hbuf, bn1, bn1 + HID,
                                                                      gamma1, beta1, H1b);

    // ---- layer 2 ----
    gemm_fused<HID><<<NBB, 256, 0, stream>>>(H1b, off, zpack, Wp2, bias2,
                                             Hbuf, bn2, bn2 + HID);

    pool_bnrelu<<<(N_NODES + 15) / 16, 256, 0, stream>>>(Hbuf, bn2, bn2 + HID, gamma2, beta2,
                                                         batch, psum);
    final_kernel<<<NGRAPH, 64, 0, stream>>>(psum, pcnt, Wf, bf, (float*)d_out);
}